// Round 4
// baseline (285.094 us; speedup 1.0000x reference)
//
#include <hip/hip_runtime.h>

#define NB 256
#define NL 512
#define NI 32
#define NH 16
#define NG 64
#define SIGD 4368
#define RING 256   // xw ring rows in LDS

__device__ __forceinline__ float RL(float v, int lane) {
  return __builtin_bit_cast(float, __builtin_amdgcn_readlane(__builtin_bit_cast(int, v), lane));
}
template<int CTRL>
__device__ __forceinline__ float QB(float v) {
  // quad_perm broadcast within each 4-lane quad (VALU DPP, no LDS)
  return __builtin_bit_cast(float, __builtin_amdgcn_update_dpp(
      0, __builtin_bit_cast(int, v), CTRL, 0xF, 0xF, true));
}
__device__ __forceinline__ int cutf(int k) {
  // segment cuts: 0,24,102,180,258,335,412,488,511. Waves 0 and 7 get the small
  // end chunks (wave0 runs the LSTM, wave7 produces xw — neither can overlap).
  switch (k) {
    case 1: return 24;  case 2: return 102; case 3: return 180; case 4: return 258;
    case 5: return 335; case 6: return 412; case 7: return 488; case 8: return 511;
    default: return 0;
  }
}

// One kernel does everything: xw production (wave7 -> LDS ring), LSTM (wave0),
// overlapped chunk signatures (all waves), Chen tree-combine, and the FC layer.
__global__ __launch_bounds__(512) void k_main(const float* __restrict__ X,
    const float* __restrict__ Wih, const float* __restrict__ bih,
    const float* __restrict__ bhh, const float* __restrict__ Whh,
    const float* __restrict__ fcw, const float* __restrict__ fcb,
    float* __restrict__ out) {
  // LDS: sm[0,8192)=h rows (512x16); phase C overlays slots there.
  //      sm[8704,8848)=9 boundary rows, later 8x10 FC partials.
  //      ring[16384]: xw ring (RING x 64), later the 4368-float sig buffer.
  __shared__ __align__(16) float sm[8848];
  __shared__ __align__(16) float ring[RING * NG];
  __shared__ int prog;    // highest h row in LDS (wave0 publishes)
  __shared__ int xprog;   // highest xw row in ring (wave7 publishes)
  float* smh = sm;
  float* bnd = sm + 8704;
  int tid = threadIdx.x;
  int wv = tid >> 6;
  int ln = tid & 63;
  int b = blockIdx.x;

  if (tid == 0) { prog = -1; xprog = -1; }
  __syncthreads();

  // ---- Producer (wave 7): xw row p = X[b,p,:]·W_ih^T + biases -> ring[p%RING].
  if (wv == 7) {
    float w2[NI];
#pragma unroll
    for (int i = 0; i < 8; ++i) {
      float4 v = *(const float4*)(Wih + ln * NI + 4 * i);
      w2[4*i+0] = v.x; w2[4*i+1] = v.y; w2[4*i+2] = v.z; w2[4*i+3] = v.w;
    }
    float bias = bih[ln] + bhh[ln];
    const float* xb = X + (size_t)b * NL * NI;
    for (int pb = 0; pb < NL; pb += 16) {
      // ring-space guard: writing row p overwrites row p-RING; safe while p <= prog+224.
      while (pb + 15 - 224 > *(volatile int*)&prog) __builtin_amdgcn_s_sleep(4);
      __asm__ __volatile__("" ::: "memory");
#pragma unroll 4
      for (int p = pb; p < pb + 16; ++p) {
        const float4* xr = (const float4*)(xb + p * NI);
        float acc = bias;
#pragma unroll
        for (int i = 0; i < 8; ++i) {
          float4 xv = xr[i];             // wave-uniform: one cache line per load
          acc += xv.x * w2[4*i+0];
          acc += xv.y * w2[4*i+1];
          acc += xv.z * w2[4*i+2];
          acc += xv.w * w2[4*i+3];
        }
        ring[(p & (RING - 1)) * NG + ln] = acc;
      }
      __asm__ __volatile__("" ::: "memory");
      if (ln == 0) *(volatile int*)&xprog = pb + 15;
    }
  }

  // ---- Phase A (wave 0): LSTM, quad layout. lane = 4*unit + gate_type (i,f,g,o).
  if (wv == 0) {
    const int q = ln & 3;
    const int j = ln >> 2;
    const int gmem = q * 16 + j;               // gate index in xw/Whh memory order
    float w[NH];
#pragma unroll
    for (int qq = 0; qq < 4; ++qq) {
      float4 v = *(const float4*)(Whh + gmem * NH + 4 * qq);
      w[4*qq+0] = v.x; w[4*qq+1] = v.y; w[4*qq+2] = v.z; w[4*qq+3] = v.w;
    }
    const bool isg = (q == 2);
    const float K  = isg ? 2.885390082f : -1.442695041f; // exp2 scale: tanh vs sigmoid
    const float Av = isg ? -2.0f : 1.0f;
    const float Bv = isg ? 1.0f : 0.0f;
    float c = 0.0f, hval = 0.0f;
    float pre[4];
    for (int tb = 0; tb < NL; tb += 16) {
      int need = tb + 19; if (need > NL - 1) need = NL - 1;
      while (*(volatile int*)&xprog < need) __builtin_amdgcn_s_sleep(1);
      __asm__ __volatile__("" ::: "memory");
      if (tb == 0) {
#pragma unroll
        for (int k = 0; k < 4; ++k) pre[k] = ring[k * NG + gmem];
      }
#pragma unroll
      for (int k = 0; k < 16; ++k) {
        int t = tb + k;
        float xval = pre[k & 3];
        // h·W_hh via v_readlane (unit j' lives on lanes 4j'..4j'+3)
        float a0 = xval, a1 = 0.f, a2 = 0.f, a3 = 0.f;
#pragma unroll
        for (int jj = 0; jj < 4; ++jj) {
          a0 += RL(hval, 16*jj + 0)  * w[4*jj + 0];
          a1 += RL(hval, 16*jj + 4)  * w[4*jj + 1];
          a2 += RL(hval, 16*jj + 8)  * w[4*jj + 2];
          a3 += RL(hval, 16*jj + 12) * w[4*jj + 3];
        }
        int tn = t + 4;
        if (tn < NL) pre[k & 3] = ring[(tn & (RING - 1)) * NG + gmem]; // 4-deep LDS prefetch
        float acc = (a0 + a1) + (a2 + a3);
        float e = __builtin_amdgcn_exp2f(K * acc);
        float r = __builtin_amdgcn_rcpf(1.0f + e);
        float val = __builtin_fmaf(Av, r, Bv);
        float iv = QB<0x00>(val);
        float fv = QB<0x55>(val);
        float gv = QB<0xAA>(val);
        float ov = QB<0xFF>(val);
        c = __builtin_fmaf(fv, c, iv * gv);
        float e2 = __builtin_amdgcn_exp2f(2.885390082f * c);
        float tc = __builtin_fmaf(-2.0f, __builtin_amdgcn_rcpf(1.0f + e2), 1.0f);
        hval = ov * tc;
        if (q == 0) smh[t * NH + j] = hval;
      }
      // plain flag publish: same-wave LDS ops complete in order; no waitcnt drain
      __asm__ __volatile__("" ::: "memory");
      if (ln == 0) *(volatile int*)&prog = tb + 15;
    }
  }

  // ---- Phase B: chunk signatures, overlapped with phase A via spin on prog.
  // Lane ln owns S3[a][b][c] for a=4m+(ln>>4), b=ln&15, c=0..15; S2[a][b] same (a,b).
  const int bi = ln & 15;
  const int hi = ln >> 4;
  int ts = cutf(wv);
  int te = cutf(wv + 1);
  while (*(volatile int*)&prog < te) __builtin_amdgcn_s_sleep(2);
  __asm__ __volatile__("" ::: "memory");

  float s3[4][16];
  float s2[4] = {0.f, 0.f, 0.f, 0.f};
#pragma unroll
  for (int m = 0; m < 4; ++m)
#pragma unroll
    for (int cc = 0; cc < 16; ++cc) s3[m][cc] = 0.f;
  float hc[16];
#pragma unroll
  for (int qq = 0; qq < 4; ++qq) {
    float4 v = *(const float4*)(smh + ts * NH + 4 * qq);
    hc[4*qq+0]=v.x; hc[4*qq+1]=v.y; hc[4*qq+2]=v.z; hc[4*qq+3]=v.w;
  }
  float hcb = smh[ts * NH + bi];
  float hca[4], h0a[4];
#pragma unroll
  for (int m = 0; m < 4; ++m) { hca[m] = smh[ts * NH + 4 * m + hi]; h0a[m] = hca[m]; }
  for (int t = ts; t < te; ++t) {
    const float* rn = smh + (t + 1) * NH;
    float hn[16];
#pragma unroll
    for (int qq = 0; qq < 4; ++qq) {
      float4 v = *(const float4*)(rn + 4 * qq);
      hn[4*qq+0]=v.x; hn[4*qq+1]=v.y; hn[4*qq+2]=v.z; hn[4*qq+3]=v.w;
    }
    float hnb = rn[bi];
    float d[16];
#pragma unroll
    for (int cc = 0; cc < 16; ++cc) d[cc] = hn[cc] - hc[cc];
    float db = hnb - hcb;
    float P[4];
#pragma unroll
    for (int m = 0; m < 4; ++m) {
      float hna = rn[4 * m + hi];
      float da = hna - hca[m];
      float s1 = hca[m] - h0a[m];                      // S1[a] pre-increment (telescoping)
      P[m] = s2[m] + db * (0.5f * s1 + 0.166666666667f * da);
      s2[m] += db * (s1 + 0.5f * da);                  // S2 += e2 + S1(x)e1
      hca[m] = hna;
    }
#pragma unroll
    for (int m = 0; m < 4; ++m)
#pragma unroll
      for (int cc = 0; cc < 16; ++cc)
        s3[m][cc] += P[m] * d[cc];                     // S3 += e3 + S2(x)e1 + S1(x)e2
#pragma unroll
    for (int cc = 0; cc < 16; ++cc) hc[cc] = hn[cc];
    hcb = hnb;
  }
  __syncthreads();

  // save boundary rows h[cut(k)] (k=0..8) before slots overwrite the h region
  if (tid < 144) {
    int k = tid >> 4, j = tid & 15;
    bnd[tid] = smh[cutf(k) * NH + j];
  }
  __syncthreads();

  // ---- Phase C: Chen tree-combine via 2 LDS slots. Slot: S2[256] then S3[4096] swizzled.
  float* slot0 = sm;
  float* slot1 = sm + 4352;
  auto writeSlot = [&](float* slot) {
#pragma unroll
    for (int m = 0; m < 4; ++m) slot[64 * m + ln] = s2[m];  // index == a*16+b
    float* s3s = slot + 256;
#pragma unroll
    for (int m = 0; m < 4; ++m)
#pragma unroll
      for (int cc = 0; cc < 16; ++cc)
        s3s[64 * ln + ((m * 16 + cc) ^ (ln & 31))] = s3[m][cc];
  };
  // A (regs) <- A ⊗ B (slot). Segments in bnd-row indices: A=[as,ae], B=[bs,be] (ae==bs).
  auto combineSlot = [&](const float* slot, int as_, int ae_, int bs_, int be_) {
    const float* s2b = slot;
    const float* s3b = slot + 256;
    float s1b[16];
#pragma unroll
    for (int cc = 0; cc < 16; ++cc) s1b[cc] = bnd[be_ * 16 + cc] - bnd[bs_ * 16 + cc];
    float s1bb = bnd[be_ * 16 + bi] - bnd[bs_ * 16 + bi];
    float s1aa[4];
#pragma unroll
    for (int m = 0; m < 4; ++m) {
      int a = 4 * m + hi;
      s1aa[m] = bnd[ae_ * 16 + a] - bnd[as_ * 16 + a];
    }
    float row[16];
#pragma unroll
    for (int cc = 0; cc < 16; ++cc) row[cc] = s2b[bi * 16 + cc];
#pragma unroll
    for (int m = 0; m < 4; ++m) {
      float s2bo = s2b[64 * m + ln];
#pragma unroll
      for (int cc = 0; cc < 16; ++cc)
        s3[m][cc] += s3b[64 * ln + ((m * 16 + cc) ^ (ln & 31))]
                   + s2[m] * s1b[cc] + s1aa[m] * row[cc];   // uses OLD s2 (S2a)
      s2[m] += s2bo + s1aa[m] * s1bb;
    }
  };
  // Round 1a: (0,1) and (2,3)
  if (wv == 1) writeSlot(slot0);
  if (wv == 3) writeSlot(slot1);
  __syncthreads();
  if (wv == 0) combineSlot(slot0, 0, 1, 1, 2);
  if (wv == 2) combineSlot(slot1, 2, 3, 3, 4);
  __syncthreads();
  // Round 1b: (4,5) and (6,7)
  if (wv == 5) writeSlot(slot0);
  if (wv == 7) writeSlot(slot1);
  __syncthreads();
  if (wv == 4) combineSlot(slot0, 4, 5, 5, 6);
  if (wv == 6) combineSlot(slot1, 6, 7, 7, 8);
  __syncthreads();
  // Round 2: (01,23) and (45,67)
  if (wv == 2) writeSlot(slot0);
  if (wv == 6) writeSlot(slot1);
  __syncthreads();
  if (wv == 0) combineSlot(slot0, 0, 2, 2, 4);
  if (wv == 4) combineSlot(slot1, 4, 6, 6, 8);
  __syncthreads();
  // Round 3: (0123, 4567)
  if (wv == 4) writeSlot(slot0);
  __syncthreads();
  if (wv == 0) {
    combineSlot(slot0, 0, 4, 4, 8);
    // write sig = [S1(16) | S2(256) | S3(4096)] into the (dead) ring buffer in LDS
    float* sb = ring;
    if (ln < 16) sb[ln] = bnd[8 * 16 + ln] - bnd[ln];   // S1 = h[511]-h[0]
#pragma unroll
    for (int m = 0; m < 4; ++m) sb[16 + 64 * m + ln] = s2[m];
#pragma unroll
    for (int m = 0; m < 4; ++m) {
#pragma unroll
      for (int qq = 0; qq < 4; ++qq) {
        float4 v;
        v.x = s3[m][4*qq+0]; v.y = s3[m][4*qq+1]; v.z = s3[m][4*qq+2]; v.w = s3[m][4*qq+3];
        *(float4*)(sb + 272 + 1024 * m + 256 * hi + 16 * bi + 4 * qq) = v;
      }
    }
  }
  __syncthreads();

  // ---- Phase D: FC. out[b][o] = sig·fc_w[o] + fc_b[o], all 512 threads.
  {
    float acc[10];
#pragma unroll
    for (int o = 0; o < 10; ++o) acc[o] = 0.f;
    for (int k = tid; k < SIGD; k += 512) {
      float s = ring[k];
#pragma unroll
      for (int o = 0; o < 10; ++o) acc[o] += s * fcw[o * SIGD + k];
    }
#pragma unroll
    for (int o = 0; o < 10; ++o) {
      float v = acc[o];
#pragma unroll
      for (int off = 32; off > 0; off >>= 1) v += __shfl_down(v, off);
      if (ln == 0) bnd[wv * 10 + o] = v;    // bnd region is dead after phase C
    }
    __syncthreads();
    if (tid < 10) {
      float s = fcb[tid];
#pragma unroll
      for (int w = 0; w < 8; ++w) s += bnd[w * 10 + tid];
      out[b * 10 + tid] = s;
    }
  }
}

extern "C" void kernel_launch(void* const* d_in, const int* in_sizes, int n_in,
                              void* d_out, int out_size, void* d_ws, size_t ws_size,
                              hipStream_t stream) {
  const float* X   = (const float*)d_in[0];
  const float* Wih = (const float*)d_in[1];
  const float* Whh = (const float*)d_in[2];
  const float* bih = (const float*)d_in[3];
  const float* bhh = (const float*)d_in[4];
  const float* fcw = (const float*)d_in[5];
  const float* fcb = (const float*)d_in[6];
  float* out = (float*)d_out;
  k_main<<<NB, 512, 0, stream>>>(X, Wih, bih, bhh, Whh, fcw, fcb, out);
}

// Round 5
// 237.443 us; speedup vs baseline: 1.2007x; 1.2007x over previous
//
#include <hip/hip_runtime.h>

#define NB 256
#define NL 512
#define NI 32
#define NH 16
#define NG 64
#define SIGD 4368

__device__ __forceinline__ float RL(float v, int lane) {
  return __builtin_bit_cast(float, __builtin_amdgcn_readlane(__builtin_bit_cast(int, v), lane));
}
template<int CTRL>
__device__ __forceinline__ float QB(float v) {
  // quad_perm broadcast within each 4-lane quad (VALU DPP, no LDS)
  return __builtin_bit_cast(float, __builtin_amdgcn_update_dpp(
      0, __builtin_bit_cast(int, v), CTRL, 0xF, 0xF, true));
}
__device__ __forceinline__ int cutf(int k) {
  // chunk cuts: geometric-ish (early chunks start earlier so they can be longer).
  // chunks 0..5 -> waves 1..6; chunk 6 -> wave 0; chunk 7 -> wave 7 (tail chunks
  // are small: they only become available when the LSTM finishes).
  switch (k) {
    case 1: return 155; case 2: return 255; case 3: return 330; case 4: return 390;
    case 5: return 435; case 6: return 470; case 7: return 493; case 8: return 511;
    default: return 0;
  }
}

// Single kernel: X->LDS stage, LSTM with inline input projection (wave 0),
// overlapped chunk signatures, Chen tree-combine, FC epilogue.
__global__ __launch_bounds__(512, 2) void k_main(const float* __restrict__ X,
    const float* __restrict__ Wih, const float* __restrict__ bih,
    const float* __restrict__ bhh, const float* __restrict__ Whh,
    const float* __restrict__ fcw, const float* __restrict__ fcb,
    float* __restrict__ out) {
  // LDS: sm[0,8192)=h rows (512x16); phase C overlays combine slots there.
  //      sm[8704,8848)=9 boundary rows, later 8x10 FC partials.
  //      xbuf[16384]: X[b] staged (512 rows x 32); later the sig buffer.
  __shared__ __align__(16) float sm[8848];
  __shared__ __align__(16) float xbuf[NL * NI];
  __shared__ int prog;    // highest h row in LDS (wave0 publishes)
  float* smh = sm;
  float* bnd = sm + 8704;
  int tid = threadIdx.x;
  int wv = tid >> 6;
  int ln = tid & 63;
  int b = blockIdx.x;

  if (tid == 0) prog = -1;

  // ---- Phase 0: stage X[b] (64 KB) into LDS, all 512 threads, coalesced float4.
  {
    const float4* Xb4 = (const float4*)(X + (size_t)b * NL * NI);
    float4* xb4 = (float4*)xbuf;
#pragma unroll
    for (int i = 0; i < 8; ++i) xb4[tid + 512 * i] = Xb4[tid + 512 * i];
  }
  __syncthreads();

  // ---- Phase A (wave 0): LSTM, quad layout. lane = 4*unit + gate_type (i,f,g,o).
  // Input projection computed inline: W_ih row register-stationary, X row from
  // LDS via uniform (broadcast) ds_read_b128, double-buffered one row ahead.
  if (wv == 0) {
    const int q = ln & 3;
    const int j = ln >> 2;
    const int gmem = q * 16 + j;               // gate index in W/bias memory order
    float w2[NI];                              // W_ih row for this gate
#pragma unroll
    for (int i = 0; i < 8; ++i) {
      float4 v = *(const float4*)(Wih + gmem * NI + 4 * i);
      w2[4*i+0] = v.x; w2[4*i+1] = v.y; w2[4*i+2] = v.z; w2[4*i+3] = v.w;
    }
    float w[NH];                               // W_hh row
#pragma unroll
    for (int qq = 0; qq < 4; ++qq) {
      float4 v = *(const float4*)(Whh + gmem * NH + 4 * qq);
      w[4*qq+0] = v.x; w[4*qq+1] = v.y; w[4*qq+2] = v.z; w[4*qq+3] = v.w;
    }
    float bias = bih[gmem] + bhh[gmem];
    const bool isg = (q == 2);
    const float K  = isg ? 2.885390082f : -1.442695041f; // exp2 scale: tanh vs sigmoid
    const float Av = isg ? -2.0f : 1.0f;
    const float Bv = isg ? 1.0f : 0.0f;
    float c = 0.0f, hval = 0.0f;
    float4 xa[8], xb_[8];
#pragma unroll
    for (int i = 0; i < 8; ++i) xa[i] = *(const float4*)(xbuf + 4 * i); // row 0
    for (int tb = 0; tb < NL; tb += 16) {
#pragma unroll
      for (int k = 0; k < 16; ++k) {
        int t = tb + k;
        float4* cur = (k & 1) ? xb_ : xa;
        float4* nxt = (k & 1) ? xa : xb_;
        // issue next row's uniform LDS loads (broadcast, conflict-free)
        if (t + 1 < NL) {
          const float* rnx = xbuf + (t + 1) * NI;
#pragma unroll
          for (int i = 0; i < 8; ++i) nxt[i] = *(const float4*)(rnx + 4 * i);
        }
        // inline input projection: 4 independent FMA chains of 8
        float xv0 = bias, xv1 = 0.f, xv2 = 0.f, xv3 = 0.f;
#pragma unroll
        for (int i = 0; i < 8; ++i) {
          xv0 += cur[i].x * w2[4*i+0];
          xv1 += cur[i].y * w2[4*i+1];
          xv2 += cur[i].z * w2[4*i+2];
          xv3 += cur[i].w * w2[4*i+3];
        }
        // h·W_hh via v_readlane (unit j' replicated on lanes 4j'..4j'+3)
        float a0 = (xv0 + xv1) + (xv2 + xv3), a1 = 0.f, a2 = 0.f, a3 = 0.f;
#pragma unroll
        for (int jj = 0; jj < 4; ++jj) {
          a0 += RL(hval, 16*jj + 0)  * w[4*jj + 0];
          a1 += RL(hval, 16*jj + 4)  * w[4*jj + 1];
          a2 += RL(hval, 16*jj + 8)  * w[4*jj + 2];
          a3 += RL(hval, 16*jj + 12) * w[4*jj + 3];
        }
        float acc = (a0 + a1) + (a2 + a3);
        float e = __builtin_amdgcn_exp2f(K * acc);
        float r = __builtin_amdgcn_rcpf(1.0f + e);
        float val = __builtin_fmaf(Av, r, Bv);
        float iv = QB<0x00>(val);
        float fv = QB<0x55>(val);
        float gv = QB<0xAA>(val);
        float ov = QB<0xFF>(val);
        c = __builtin_fmaf(fv, c, iv * gv);
        float e2 = __builtin_amdgcn_exp2f(2.885390082f * c);
        float tc = __builtin_fmaf(-2.0f, __builtin_amdgcn_rcpf(1.0f + e2), 1.0f);
        hval = ov * tc;
        if (q == 0) smh[t * NH + j] = hval;
      }
      // plain flag publish: same-wave LDS ops complete in order; no waitcnt drain
      __asm__ __volatile__("" ::: "memory");
      if (ln == 0) *(volatile int*)&prog = tb + 15;
    }
  }

  // ---- Phase B: chunk signatures, overlapped with phase A via spin on prog.
  // Lane ln owns S3[a][b][c] for a=4m+(ln>>4), b=ln&15, c=0..15; S2[a][b] same (a,b).
  const int bi = ln & 15;
  const int hi = ln >> 4;
  const int ch = (wv == 0) ? 6 : (wv == 7) ? 7 : (wv - 1);   // chunk owned by this wave
  int ts = cutf(ch);
  int te = cutf(ch + 1);
  while (*(volatile int*)&prog < te) __builtin_amdgcn_s_sleep(2);
  __asm__ __volatile__("" ::: "memory");

  float s3[4][16];
  float s2[4] = {0.f, 0.f, 0.f, 0.f};
#pragma unroll
  for (int m = 0; m < 4; ++m)
#pragma unroll
    for (int cc = 0; cc < 16; ++cc) s3[m][cc] = 0.f;
  float hc[16];
#pragma unroll
  for (int qq = 0; qq < 4; ++qq) {
    float4 v = *(const float4*)(smh + ts * NH + 4 * qq);
    hc[4*qq+0]=v.x; hc[4*qq+1]=v.y; hc[4*qq+2]=v.z; hc[4*qq+3]=v.w;
  }
  float hcb = smh[ts * NH + bi];
  float hca[4], h0a[4];
#pragma unroll
  for (int m = 0; m < 4; ++m) { hca[m] = smh[ts * NH + 4 * m + hi]; h0a[m] = hca[m]; }
  for (int t = ts; t < te; ++t) {
    const float* rn = smh + (t + 1) * NH;
    float hn[16];
#pragma unroll
    for (int qq = 0; qq < 4; ++qq) {
      float4 v = *(const float4*)(rn + 4 * qq);
      hn[4*qq+0]=v.x; hn[4*qq+1]=v.y; hn[4*qq+2]=v.z; hn[4*qq+3]=v.w;
    }
    float hnb = rn[bi];
    float d[16];
#pragma unroll
    for (int cc = 0; cc < 16; ++cc) d[cc] = hn[cc] - hc[cc];
    float db = hnb - hcb;
    float P[4];
#pragma unroll
    for (int m = 0; m < 4; ++m) {
      float hna = rn[4 * m + hi];
      float da = hna - hca[m];
      float s1 = hca[m] - h0a[m];                      // S1[a] pre-increment (telescoping)
      P[m] = s2[m] + db * (0.5f * s1 + 0.166666666667f * da);
      s2[m] += db * (s1 + 0.5f * da);                  // S2 += e2 + S1(x)e1
      hca[m] = hna;
    }
#pragma unroll
    for (int m = 0; m < 4; ++m)
#pragma unroll
      for (int cc = 0; cc < 16; ++cc)
        s3[m][cc] += P[m] * d[cc];                     // S3 += e3 + S2(x)e1 + S1(x)e2
#pragma unroll
    for (int cc = 0; cc < 16; ++cc) hc[cc] = hn[cc];
    hcb = hnb;
  }
  __syncthreads();

  // save boundary rows h[cut(k)] (k=0..8) before slots overwrite the h region
  if (tid < 144) {
    int k = tid >> 4, j = tid & 15;
    bnd[tid] = smh[cutf(k) * NH + j];
  }
  __syncthreads();

  // ---- Phase C: Chen tree-combine via 2 LDS slots. Slot: S2[256] then S3[4096] swizzled.
  float* slot0 = sm;
  float* slot1 = sm + 4352;
  auto writeSlot = [&](float* slot) {
#pragma unroll
    for (int m = 0; m < 4; ++m) slot[64 * m + ln] = s2[m];  // index == a*16+b
    float* s3s = slot + 256;
#pragma unroll
    for (int m = 0; m < 4; ++m)
#pragma unroll
      for (int cc = 0; cc < 16; ++cc)
        s3s[64 * ln + ((m * 16 + cc) ^ (ln & 31))] = s3[m][cc];
  };
  // A (regs) <- A ⊗ B (slot). Segments in bnd-row indices: A=[as,ae], B=[bs,be] (ae==bs).
  auto combineSlot = [&](const float* slot, int as_, int ae_, int bs_, int be_) {
    const float* s2b = slot;
    const float* s3b = slot + 256;
    float s1b[16];
#pragma unroll
    for (int cc = 0; cc < 16; ++cc) s1b[cc] = bnd[be_ * 16 + cc] - bnd[bs_ * 16 + cc];
    float s1bb = bnd[be_ * 16 + bi] - bnd[bs_ * 16 + bi];
    float s1aa[4];
#pragma unroll
    for (int m = 0; m < 4; ++m) {
      int a = 4 * m + hi;
      s1aa[m] = bnd[ae_ * 16 + a] - bnd[as_ * 16 + a];
    }
    float row[16];
#pragma unroll
    for (int cc = 0; cc < 16; ++cc) row[cc] = s2b[bi * 16 + cc];
#pragma unroll
    for (int m = 0; m < 4; ++m) {
      float s2bo = s2b[64 * m + ln];
#pragma unroll
      for (int cc = 0; cc < 16; ++cc)
        s3[m][cc] += s3b[64 * ln + ((m * 16 + cc) ^ (ln & 31))]
                   + s2[m] * s1b[cc] + s1aa[m] * row[cc];   // uses OLD s2 (S2a)
      s2[m] += s2bo + s1aa[m] * s1bb;
    }
  };
  // Round 1a: chunks (0,1) and (2,3)
  if (ch == 1) writeSlot(slot0);
  if (ch == 3) writeSlot(slot1);
  __syncthreads();
  if (ch == 0) combineSlot(slot0, 0, 1, 1, 2);
  if (ch == 2) combineSlot(slot1, 2, 3, 3, 4);
  __syncthreads();
  // Round 1b: chunks (4,5) and (6,7)
  if (ch == 5) writeSlot(slot0);
  if (ch == 7) writeSlot(slot1);
  __syncthreads();
  if (ch == 4) combineSlot(slot0, 4, 5, 5, 6);
  if (ch == 6) combineSlot(slot1, 6, 7, 7, 8);
  __syncthreads();
  // Round 2: (01,23) and (45,67)
  if (ch == 2) writeSlot(slot0);
  if (ch == 6) writeSlot(slot1);
  __syncthreads();
  if (ch == 0) combineSlot(slot0, 0, 2, 2, 4);
  if (ch == 4) combineSlot(slot1, 4, 6, 6, 8);
  __syncthreads();
  // Round 3: (0123, 4567)
  if (ch == 4) writeSlot(slot0);
  __syncthreads();
  if (ch == 0) {
    combineSlot(slot0, 0, 4, 4, 8);
    // write sig = [S1(16) | S2(256) | S3(4096)] into the (dead) xbuf in LDS
    float* sb = xbuf;
    if (ln < 16) sb[ln] = bnd[8 * 16 + ln] - bnd[ln];   // S1 = h[511]-h[0]
#pragma unroll
    for (int m = 0; m < 4; ++m) sb[16 + 64 * m + ln] = s2[m];
#pragma unroll
    for (int m = 0; m < 4; ++m) {
#pragma unroll
      for (int qq = 0; qq < 4; ++qq) {
        float4 v;
        v.x = s3[m][4*qq+0]; v.y = s3[m][4*qq+1]; v.z = s3[m][4*qq+2]; v.w = s3[m][4*qq+3];
        *(float4*)(sb + 272 + 1024 * m + 256 * hi + 16 * bi + 4 * qq) = v;
      }
    }
  }
  __syncthreads();

  // ---- Phase D: FC. out[b][o] = sig·fc_w[o] + fc_b[o], all 512 threads.
  {
    float acc[10];
#pragma unroll
    for (int o = 0; o < 10; ++o) acc[o] = 0.f;
    for (int k = tid; k < SIGD; k += 512) {
      float s = xbuf[k];
#pragma unroll
      for (int o = 0; o < 10; ++o) acc[o] += s * fcw[o * SIGD + k];
    }
#pragma unroll
    for (int o = 0; o < 10; ++o) {
      float v = acc[o];
#pragma unroll
      for (int off = 32; off > 0; off >>= 1) v += __shfl_down(v, off);
      if (ln == 0) bnd[wv * 10 + o] = v;    // bnd region is dead after phase C
    }
    __syncthreads();
    if (tid < 10) {
      float s = fcb[tid];
#pragma unroll
      for (int w = 0; w < 8; ++w) s += bnd[w * 10 + tid];
      out[b * 10 + tid] = s;
    }
  }
}

extern "C" void kernel_launch(void* const* d_in, const int* in_sizes, int n_in,
                              void* d_out, int out_size, void* d_ws, size_t ws_size,
                              hipStream_t stream) {
  const float* X   = (const float*)d_in[0];
  const float* Wih = (const float*)d_in[1];
  const float* Whh = (const float*)d_in[2];
  const float* bih = (const float*)d_in[3];
  const float* bhh = (const float*)d_in[4];
  const float* fcw = (const float*)d_in[5];
  const float* fcb = (const float*)d_in[6];
  float* out = (float*)d_out;
  k_main<<<NB, 512, 0, stream>>>(X, Wih, bih, bhh, Whh, fcw, fcb, out);
}

// Round 6
// 229.145 us; speedup vs baseline: 1.2442x; 1.0362x over previous
//
#include <hip/hip_runtime.h>

#define NB 256
#define NL 512
#define NI 32
#define NH 16
#define NG 64
#define SIGD 4368

template<int CTRL>
__device__ __forceinline__ float QB(float v) {
  // quad_perm broadcast within each 4-lane quad (VALU DPP, no LDS)
  return __builtin_bit_cast(float, __builtin_amdgcn_update_dpp(
      0, __builtin_bit_cast(int, v), CTRL, 0xF, 0xF, true));
}
__device__ __forceinline__ int cutf(int k) {
  // equal streaming chunks for waves 1..7; wave 0 gets the small tail (493-511)
  switch (k) {
    case 1: return 71;  case 2: return 142; case 3: return 212; case 4: return 282;
    case 5: return 352; case 6: return 422; case 7: return 493; case 8: return 511;
    default: return 0;
  }
}

// Single kernel: LSTM with inline input projection (wave 0, global X loads,
// LDS-roundtrip matvec), streaming chunk signatures, Chen tree-combine, FC.
__global__ __launch_bounds__(512, 2) void k_main(const float* __restrict__ X,
    const float* __restrict__ Wih, const float* __restrict__ bih,
    const float* __restrict__ bhh, const float* __restrict__ Whh,
    const float* __restrict__ fcw, const float* __restrict__ fcb,
    float* __restrict__ out) {
  // LDS: sm[0,16)=zero row ("row -1"); sm[16,8208)=h rows (512x16).
  //      Phase C overlays slot0=sm[0,4352), slot1=sm[4352,8704).
  //      sm[8704,8848)=9 boundary rows, later 8x10 FC partials.
  //      sigb[4368]: final signature for the FC phase.
  __shared__ __align__(16) float sm[8848];
  __shared__ __align__(16) float sigb[SIGD];
  __shared__ int prog;    // highest h row in LDS (wave0 publishes every 16)
  float* smh = sm + 16;   // row t at smh + t*16; t-1 for t=0 hits the zero row
  float* bnd = sm + 8704;
  int tid = threadIdx.x;
  int wv = tid >> 6;
  int ln = tid & 63;
  int b = blockIdx.x;

  if (tid < 16) sm[tid] = 0.0f;          // zero row ("h[-1]")
  if (tid == 0) prog = -1;
  __syncthreads();

  // ---- Wave 1: warm X[b] (64 KB) into this CU's L2 before wave 0 streams it.
  if (wv == 1) {
    const float4* Xb = (const float4*)(X + (size_t)b * NL * NI);
    float s = 0.f;
    for (int i = ln; i < NL * NI / 4; i += 64) {
      float4 v = Xb[i];
      s += v.x + v.y + v.z + v.w;
    }
    if (s == 1234.5678f) sigb[0] = s;    // un-DCE guard; sigb fully rewritten later
  }

  // ---- Phase A (wave 0): LSTM, quad layout. lane = 4*unit + gate_type (i,f,g,o).
  if (wv == 0) {
    const int q = ln & 3;
    const int j = ln >> 2;
    const int gmem = q * 16 + j;               // gate index in W/bias memory order
    float w2[NI];                              // W_ih row (register-stationary)
#pragma unroll
    for (int i = 0; i < 8; ++i) {
      float4 v = *(const float4*)(Wih + gmem * NI + 4 * i);
      w2[4*i+0] = v.x; w2[4*i+1] = v.y; w2[4*i+2] = v.z; w2[4*i+3] = v.w;
    }
    float w[NH];                               // W_hh row
#pragma unroll
    for (int qq = 0; qq < 4; ++qq) {
      float4 v = *(const float4*)(Whh + gmem * NH + 4 * qq);
      w[4*qq+0] = v.x; w[4*qq+1] = v.y; w[4*qq+2] = v.z; w[4*qq+3] = v.w;
    }
    float bias = bih[gmem] + bhh[gmem];
    const bool isg = (q == 2);
    const float K  = isg ? 2.885390082f : -1.442695041f; // exp2 scale: tanh vs sigmoid
    const float Av = isg ? -2.0f : 1.0f;
    const float Bv = isg ? 1.0f : 0.0f;
    const float* xb = X + (size_t)b * NL * NI;
    // X row pipeline: bufA/bufB, 2 rows ahead; xval computed one step ahead.
    float4 bufA[8], bufB[8];
#pragma unroll
    for (int i = 0; i < 8; ++i) bufA[i] = *(const float4*)(xb + 4 * i);        // row 0
#pragma unroll
    for (int i = 0; i < 8; ++i) bufB[i] = *(const float4*)(xb + NI + 4 * i);   // row 1
    float xval;
    {
      float x0 = bias, x1 = 0.f, x2 = 0.f, x3 = 0.f;
#pragma unroll
      for (int i = 0; i < 8; ++i) {
        x0 += bufA[i].x * w2[4*i+0]; x1 += bufA[i].y * w2[4*i+1];
        x2 += bufA[i].z * w2[4*i+2]; x3 += bufA[i].w * w2[4*i+3];
      }
      xval = (x0 + x1) + (x2 + x3);            // xval(0)
    }
    float c = 0.0f, hval = 0.0f;
    for (int tb = 0; tb < NL; tb += 16) {
#pragma unroll
      for (int k = 0; k < 16; ++k) {
        int t = tb + k;
        float4* ld = (k & 1) ? bufB : bufA;    // receives row t+2
        float4* cn = (k & 1) ? bufA : bufB;    // holds row t+1
        if (t + 2 < NL) {
          const float* rx = xb + (t + 2) * NI;
#pragma unroll
          for (int i = 0; i < 8; ++i) ld[i] = *(const float4*)(rx + 4 * i);
        }
        // h·W_hh: uniform (broadcast) read of h row t-1 — no readlanes on chain
        const float4* hp = (const float4*)(smh + (t - 1) * NH);
        float4 h0 = hp[0], h1 = hp[1], h2 = hp[2], h3 = hp[3];
        float a0 = xval, a1 = 0.f, a2 = 0.f, a3 = 0.f;
        a0 += h0.x * w[0];  a1 += h0.y * w[1];  a2 += h0.z * w[2];  a3 += h0.w * w[3];
        a0 += h1.x * w[4];  a1 += h1.y * w[5];  a2 += h1.z * w[6];  a3 += h1.w * w[7];
        a0 += h2.x * w[8];  a1 += h2.y * w[9];  a2 += h2.z * w[10]; a3 += h2.w * w[11];
        a0 += h3.x * w[12]; a1 += h3.y * w[13]; a2 += h3.z * w[14]; a3 += h3.w * w[15];
        float acc = (a0 + a1) + (a2 + a3);
        float e = __builtin_amdgcn_exp2f(K * acc);
        float r = __builtin_amdgcn_rcpf(1.0f + e);
        float val = __builtin_fmaf(Av, r, Bv);
        float iv = QB<0x00>(val);
        float fv = QB<0x55>(val);
        float gv = QB<0xAA>(val);
        float ov = QB<0xFF>(val);
        c = __builtin_fmaf(fv, c, iv * gv);
        float e2 = __builtin_amdgcn_exp2f(2.885390082f * c);
        float tc = __builtin_fmaf(-2.0f, __builtin_amdgcn_rcpf(1.0f + e2), 1.0f);
        hval = ov * tc;
        if (q == 0) smh[t * NH + j] = hval;
        // next step's xval (off-chain, fills stall slots)
        float x0 = bias, x1 = 0.f, x2 = 0.f, x3 = 0.f;
#pragma unroll
        for (int i = 0; i < 8; ++i) {
          x0 += cn[i].x * w2[4*i+0]; x1 += cn[i].y * w2[4*i+1];
          x2 += cn[i].z * w2[4*i+2]; x3 += cn[i].w * w2[4*i+3];
        }
        xval = (x0 + x1) + (x2 + x3);
      }
      // plain flag publish: same-wave LDS ops complete in order; no waitcnt drain
      __asm__ __volatile__("" ::: "memory");
      if (ln == 0) *(volatile int*)&prog = tb + 15;
    }
  }

  // ---- Phase B: streaming chunk signatures (process rows as wave0 publishes).
  // Lane ln owns S3[a][b][c] for a=4m+(ln>>4), b=ln&15, c=0..15; S2[a][b] same (a,b).
  const int bi = ln & 15;
  const int hi = ln >> 4;
  const int ch = (wv == 0) ? 7 : (wv - 1);   // chunk owned by this wave
  int ts = cutf(ch);
  int te = cutf(ch + 1);
  while (*(volatile int*)&prog < ts) __builtin_amdgcn_s_sleep(1);
  __asm__ __volatile__("" ::: "memory");

  float s3[4][16];
  float s2[4] = {0.f, 0.f, 0.f, 0.f};
#pragma unroll
  for (int m = 0; m < 4; ++m)
#pragma unroll
    for (int cc = 0; cc < 16; ++cc) s3[m][cc] = 0.f;
  float hc[16];
#pragma unroll
  for (int qq = 0; qq < 4; ++qq) {
    float4 v = *(const float4*)(smh + ts * NH + 4 * qq);
    hc[4*qq+0]=v.x; hc[4*qq+1]=v.y; hc[4*qq+2]=v.z; hc[4*qq+3]=v.w;
  }
  float hcb = smh[ts * NH + bi];
  float hca[4], h0a[4];
#pragma unroll
  for (int m = 0; m < 4; ++m) { hca[m] = smh[ts * NH + 4 * m + hi]; h0a[m] = hca[m]; }
  for (int t = ts; t < te; ++t) {
    while (*(volatile int*)&prog < t + 1) __builtin_amdgcn_s_sleep(1);  // stream
    __asm__ __volatile__("" ::: "memory");
    const float* rn = smh + (t + 1) * NH;
    float hn[16];
#pragma unroll
    for (int qq = 0; qq < 4; ++qq) {
      float4 v = *(const float4*)(rn + 4 * qq);
      hn[4*qq+0]=v.x; hn[4*qq+1]=v.y; hn[4*qq+2]=v.z; hn[4*qq+3]=v.w;
    }
    float hnb = rn[bi];
    float d[16];
#pragma unroll
    for (int cc = 0; cc < 16; ++cc) d[cc] = hn[cc] - hc[cc];
    float db = hnb - hcb;
    float P[4];
#pragma unroll
    for (int m = 0; m < 4; ++m) {
      float hna = rn[4 * m + hi];
      float da = hna - hca[m];
      float s1 = hca[m] - h0a[m];                      // S1[a] pre-increment (telescoping)
      P[m] = s2[m] + db * (0.5f * s1 + 0.166666666667f * da);
      s2[m] += db * (s1 + 0.5f * da);                  // S2 += e2 + S1(x)e1
      hca[m] = hna;
    }
#pragma unroll
    for (int m = 0; m < 4; ++m)
#pragma unroll
      for (int cc = 0; cc < 16; ++cc)
        s3[m][cc] += P[m] * d[cc];                     // S3 += e3 + S2(x)e1 + S1(x)e2
#pragma unroll
    for (int cc = 0; cc < 16; ++cc) hc[cc] = hn[cc];
    hcb = hnb;
  }
  __syncthreads();

  // save boundary rows h[cut(k)] (k=0..8) before slots overwrite the h region
  if (tid < 144) {
    int k = tid >> 4, j = tid & 15;
    bnd[tid] = smh[cutf(k) * NH + j];
  }
  __syncthreads();

  // ---- Phase C: Chen tree-combine via 2 LDS slots. Slot: S2[256] then S3[4096] swizzled.
  float* slot0 = sm;
  float* slot1 = sm + 4352;
  auto writeSlot = [&](float* slot) {
#pragma unroll
    for (int m = 0; m < 4; ++m) slot[64 * m + ln] = s2[m];  // index == a*16+b
    float* s3s = slot + 256;
#pragma unroll
    for (int m = 0; m < 4; ++m)
#pragma unroll
      for (int cc = 0; cc < 16; ++cc)
        s3s[64 * ln + ((m * 16 + cc) ^ (ln & 31))] = s3[m][cc];
  };
  // A (regs) <- A ⊗ B (slot). Segments in bnd-row indices: A=[as,ae], B=[bs,be] (ae==bs).
  auto combineSlot = [&](const float* slot, int as_, int ae_, int bs_, int be_) {
    const float* s2b = slot;
    const float* s3b = slot + 256;
    float s1b[16];
#pragma unroll
    for (int cc = 0; cc < 16; ++cc) s1b[cc] = bnd[be_ * 16 + cc] - bnd[bs_ * 16 + cc];
    float s1bb = bnd[be_ * 16 + bi] - bnd[bs_ * 16 + bi];
    float s1aa[4];
#pragma unroll
    for (int m = 0; m < 4; ++m) {
      int a = 4 * m + hi;
      s1aa[m] = bnd[ae_ * 16 + a] - bnd[as_ * 16 + a];
    }
    float row[16];
#pragma unroll
    for (int cc = 0; cc < 16; ++cc) row[cc] = s2b[bi * 16 + cc];
#pragma unroll
    for (int m = 0; m < 4; ++m) {
      float s2bo = s2b[64 * m + ln];
#pragma unroll
      for (int cc = 0; cc < 16; ++cc)
        s3[m][cc] += s3b[64 * ln + ((m * 16 + cc) ^ (ln & 31))]
                   + s2[m] * s1b[cc] + s1aa[m] * row[cc];   // uses OLD s2 (S2a)
      s2[m] += s2bo + s1aa[m] * s1bb;
    }
  };
  // Round 1a: chunks (0,1) and (2,3)
  if (ch == 1) writeSlot(slot0);
  if (ch == 3) writeSlot(slot1);
  __syncthreads();
  if (ch == 0) combineSlot(slot0, 0, 1, 1, 2);
  if (ch == 2) combineSlot(slot1, 2, 3, 3, 4);
  __syncthreads();
  // Round 1b: chunks (4,5) and (6,7)
  if (ch == 5) writeSlot(slot0);
  if (ch == 7) writeSlot(slot1);
  __syncthreads();
  if (ch == 4) combineSlot(slot0, 4, 5, 5, 6);
  if (ch == 6) combineSlot(slot1, 6, 7, 7, 8);
  __syncthreads();
  // Round 2: (01,23) and (45,67)
  if (ch == 2) writeSlot(slot0);
  if (ch == 6) writeSlot(slot1);
  __syncthreads();
  if (ch == 0) combineSlot(slot0, 0, 2, 2, 4);
  if (ch == 4) combineSlot(slot1, 4, 6, 6, 8);
  __syncthreads();
  // Round 3: (0123, 4567)
  if (ch == 4) writeSlot(slot0);
  __syncthreads();
  if (ch == 0) {
    combineSlot(slot0, 0, 4, 4, 8);
    // write sig = [S1(16) | S2(256) | S3(4096)] into LDS sig buffer
    if (ln < 16) sigb[ln] = bnd[8 * 16 + ln] - bnd[ln];   // S1 = h[511]-h[0]
#pragma unroll
    for (int m = 0; m < 4; ++m) sigb[16 + 64 * m + ln] = s2[m];
#pragma unroll
    for (int m = 0; m < 4; ++m) {
#pragma unroll
      for (int qq = 0; qq < 4; ++qq) {
        float4 v;
        v.x = s3[m][4*qq+0]; v.y = s3[m][4*qq+1]; v.z = s3[m][4*qq+2]; v.w = s3[m][4*qq+3];
        *(float4*)(sigb + 272 + 1024 * m + 256 * hi + 16 * bi + 4 * qq) = v;
      }
    }
  }
  __syncthreads();

  // ---- Phase D: FC. out[b][o] = sig·fc_w[o] + fc_b[o], all 512 threads.
  {
    float acc[10];
#pragma unroll
    for (int o = 0; o < 10; ++o) acc[o] = 0.f;
    for (int k = tid; k < SIGD; k += 512) {
      float s = sigb[k];
#pragma unroll
      for (int o = 0; o < 10; ++o) acc[o] += s * fcw[o * SIGD + k];
    }
#pragma unroll
    for (int o = 0; o < 10; ++o) {
      float v = acc[o];
#pragma unroll
      for (int off = 32; off > 0; off >>= 1) v += __shfl_down(v, off);
      if (ln == 0) bnd[wv * 10 + o] = v;    // bnd region is dead after phase C
    }
    __syncthreads();
    if (tid < 10) {
      float s = fcb[tid];
#pragma unroll
      for (int w = 0; w < 8; ++w) s += bnd[w * 10 + tid];
      out[b * 10 + tid] = s;
    }
  }
}

extern "C" void kernel_launch(void* const* d_in, const int* in_sizes, int n_in,
                              void* d_out, int out_size, void* d_ws, size_t ws_size,
                              hipStream_t stream) {
  const float* X   = (const float*)d_in[0];
  const float* Wih = (const float*)d_in[1];
  const float* Whh = (const float*)d_in[2];
  const float* bih = (const float*)d_in[3];
  const float* bhh = (const float*)d_in[4];
  const float* fcw = (const float*)d_in[5];
  const float* fcb = (const float*)d_in[6];
  float* out = (float*)d_out;
  k_main<<<NB, 512, 0, stream>>>(X, Wih, bih, bhh, Whh, fcw, fcb, out);
}

// Round 7
// 207.997 us; speedup vs baseline: 1.3707x; 1.1017x over previous
//
#include <hip/hip_runtime.h>

#define NB 256
#define NL 512
#define NI 32
#define NH 16
#define NG 64
#define SIGD 4368

__device__ __forceinline__ float RL(float v, int lane) {
  return __builtin_bit_cast(float, __builtin_amdgcn_readlane(__builtin_bit_cast(int, v), lane));
}
template<int CTRL>
__device__ __forceinline__ float QB(float v) {
  // quad_perm broadcast within each 4-lane quad (VALU DPP, no LDS)
  return __builtin_bit_cast(float, __builtin_amdgcn_update_dpp(
      0, __builtin_bit_cast(int, v), CTRL, 0xF, 0xF, true));
}
__device__ __forceinline__ int cutf(int k) {
  // equal streaming chunks for waves 1..7; wave 0 gets the small tail (493-511)
  switch (k) {
    case 1: return 71;  case 2: return 142; case 3: return 212; case 4: return 282;
    case 5: return 352; case 6: return 422; case 7: return 493; case 8: return 511;
    default: return 0;
  }
}

// Single kernel. Phase 0: all 8 waves compute xw -> LDS (128 KB). Phase A:
// wave0 LSTM, readlane matvec, xval via 1 conflict-free ds_read/step, zero
// global loads on the chain. Phase B: streaming chunk signatures. Phase C:
// Chen tree-combine (slots overlay dead xw LDS). Phase D: FC epilogue.
__global__ __launch_bounds__(512, 1) void k_main(const float* __restrict__ X,
    const float* __restrict__ Wih, const float* __restrict__ bih,
    const float* __restrict__ bhh, const float* __restrict__ Whh,
    const float* __restrict__ fcw, const float* __restrict__ fcb,
    float* __restrict__ out) {
  // xwh[t*64 + g]: xw rows (gate-major, memory gate order). h row t overlays
  // xwh[t*64 + 0..16) once xw row t is consumed (prefetch depth 4 guarantees
  // the read happens first). Phase C overlays slot0=xwh[0,4352),
  // slot1=xwh[4352,8704), sigb=xwh[8704,13072).
  __shared__ __align__(16) float xwh[NL * NG];
  __shared__ __align__(16) float bnd[144];   // 9 boundary rows; later 8x10 FC partials
  __shared__ int prog;                       // highest h row in LDS (wave0 publishes)
  int tid = threadIdx.x;
  int wv = tid >> 6;
  int ln = tid & 63;
  int b = blockIdx.x;

  if (tid == 0) prog = -1;

  // ---- Phase 0: xw[t][g] = X[b,t,:]·W_ih[g,:] + b_ih[g] + b_hh[g] -> LDS.
  // Wave wv does rows [64wv, 64wv+64). Lane = gate (memory order). X row loads
  // are wave-uniform (broadcast). Stores are stride-1 (2-way aliasing, free).
  {
    float w2[NI];
#pragma unroll
    for (int i = 0; i < 8; ++i) {
      float4 v = *(const float4*)(Wih + ln * NI + 4 * i);
      w2[4*i+0] = v.x; w2[4*i+1] = v.y; w2[4*i+2] = v.z; w2[4*i+3] = v.w;
    }
    float bias = bih[ln] + bhh[ln];
    const float* xb = X + (size_t)b * NL * NI;
#pragma unroll 4
    for (int t = 64 * wv; t < 64 * (wv + 1); ++t) {
      const float4* xr = (const float4*)(xb + t * NI);
      float x0 = bias, x1 = 0.f, x2 = 0.f, x3 = 0.f;
#pragma unroll
      for (int i = 0; i < 8; ++i) {
        float4 xv = xr[i];
        x0 += xv.x * w2[4*i+0]; x1 += xv.y * w2[4*i+1];
        x2 += xv.z * w2[4*i+2]; x3 += xv.w * w2[4*i+3];
      }
      xwh[t * NG + ln] = (x0 + x1) + (x2 + x3);
    }
  }
  __syncthreads();

  // ---- Phase A (wave 0): LSTM, quad layout. lane = 4*unit + gate_type (i,f,g,o).
  if (wv == 0) {
    const int q = ln & 3;
    const int j = ln >> 2;
    const int gmem = q * 16 + j;               // gate index in memory order
    float w[NH];                               // W_hh row
#pragma unroll
    for (int qq = 0; qq < 4; ++qq) {
      float4 v = *(const float4*)(Whh + gmem * NH + 4 * qq);
      w[4*qq+0] = v.x; w[4*qq+1] = v.y; w[4*qq+2] = v.z; w[4*qq+3] = v.w;
    }
    const bool isg = (q == 2);
    const float K  = isg ? 2.885390082f : -1.442695041f; // exp2 scale: tanh vs sigmoid
    const float Av = isg ? -2.0f : 1.0f;
    const float Bv = isg ? 1.0f : 0.0f;
    float c = 0.0f, hval = 0.0f;
    float xpre[4];
#pragma unroll
    for (int k = 0; k < 4; ++k) xpre[k] = xwh[k * NG + gmem];   // rows 0..3
    for (int tb = 0; tb < NL; tb += 16) {
#pragma unroll
      for (int k = 0; k < 16; ++k) {
        int t = tb + k;
        float xval = xpre[k & 3];
        // h·W_hh via v_readlane (unit u on lanes 4u..4u+3); no LDS on chain
        float a0 = xval, a1 = 0.f, a2 = 0.f, a3 = 0.f;
#pragma unroll
        for (int jj = 0; jj < 4; ++jj) {
          a0 += RL(hval, 16*jj + 0)  * w[4*jj + 0];
          a1 += RL(hval, 16*jj + 4)  * w[4*jj + 1];
          a2 += RL(hval, 16*jj + 8)  * w[4*jj + 2];
          a3 += RL(hval, 16*jj + 12) * w[4*jj + 3];
        }
        // prefetch xval 4 rows ahead (off-chain, conflict-free ds_read_b32)
        if (t + 4 < NL) xpre[k & 3] = xwh[(t + 4) * NG + gmem];
        float acc = (a0 + a1) + (a2 + a3);
        float e = __builtin_amdgcn_exp2f(K * acc);
        float r = __builtin_amdgcn_rcpf(1.0f + e);
        float val = __builtin_fmaf(Av, r, Bv);
        float iv = QB<0x00>(val);
        float fv = QB<0x55>(val);
        float gv = QB<0xAA>(val);
        float ov = QB<0xFF>(val);
        c = __builtin_fmaf(fv, c, iv * gv);
        float e2 = __builtin_amdgcn_exp2f(2.885390082f * c);
        float tc = __builtin_fmaf(-2.0f, __builtin_amdgcn_rcpf(1.0f + e2), 1.0f);
        hval = ov * tc;
        if (q == 0) xwh[t * NG + j] = hval;    // h row t overlays consumed xw row t
      }
      // plain flag publish: same-wave LDS ops complete in order; no waitcnt drain
      __asm__ __volatile__("" ::: "memory");
      if (ln == 0) *(volatile int*)&prog = tb + 15;
    }
  }

  // ---- Phase B: streaming chunk signatures (h row t at xwh + t*64).
  // Lane ln owns S3[a][b][c] for a=4m+(ln>>4), b=ln&15, c=0..15; S2[a][b] same (a,b).
  const int bi = ln & 15;
  const int hi = ln >> 4;
  const int ch = (wv == 0) ? 7 : (wv - 1);   // chunk owned by this wave
  int ts = cutf(ch);
  int te = cutf(ch + 1);
  while (*(volatile int*)&prog < ts) __builtin_amdgcn_s_sleep(1);
  __asm__ __volatile__("" ::: "memory");

  float s3[4][16];
  float s2[4] = {0.f, 0.f, 0.f, 0.f};
#pragma unroll
  for (int m = 0; m < 4; ++m)
#pragma unroll
    for (int cc = 0; cc < 16; ++cc) s3[m][cc] = 0.f;
  float hc[16];
#pragma unroll
  for (int qq = 0; qq < 4; ++qq) {
    float4 v = *(const float4*)(xwh + ts * NG + 4 * qq);
    hc[4*qq+0]=v.x; hc[4*qq+1]=v.y; hc[4*qq+2]=v.z; hc[4*qq+3]=v.w;
  }
  float hcb = xwh[ts * NG + bi];
  float hca[4], h0a[4];
#pragma unroll
  for (int m = 0; m < 4; ++m) { hca[m] = xwh[ts * NG + 4 * m + hi]; h0a[m] = hca[m]; }
  for (int t = ts; t < te; ++t) {
    while (*(volatile int*)&prog < t + 1) __builtin_amdgcn_s_sleep(1);  // stream
    __asm__ __volatile__("" ::: "memory");
    const float* rn = xwh + (t + 1) * NG;
    float hn[16];
#pragma unroll
    for (int qq = 0; qq < 4; ++qq) {
      float4 v = *(const float4*)(rn + 4 * qq);
      hn[4*qq+0]=v.x; hn[4*qq+1]=v.y; hn[4*qq+2]=v.z; hn[4*qq+3]=v.w;
    }
    float hnb = rn[bi];
    float d[16];
#pragma unroll
    for (int cc = 0; cc < 16; ++cc) d[cc] = hn[cc] - hc[cc];
    float db = hnb - hcb;
    float P[4];
#pragma unroll
    for (int m = 0; m < 4; ++m) {
      float hna = rn[4 * m + hi];
      float da = hna - hca[m];
      float s1 = hca[m] - h0a[m];                      // S1[a] pre-increment (telescoping)
      P[m] = s2[m] + db * (0.5f * s1 + 0.166666666667f * da);
      s2[m] += db * (s1 + 0.5f * da);                  // S2 += e2 + S1(x)e1
      hca[m] = hna;
    }
#pragma unroll
    for (int m = 0; m < 4; ++m)
#pragma unroll
      for (int cc = 0; cc < 16; ++cc)
        s3[m][cc] += P[m] * d[cc];                     // S3 += e3 + S2(x)e1 + S1(x)e2
#pragma unroll
    for (int cc = 0; cc < 16; ++cc) hc[cc] = hn[cc];
    hcb = hnb;
  }
  __syncthreads();

  // save boundary rows h[cut(k)] (k=0..8) before slots overwrite the region
  if (tid < 144) {
    int k = tid >> 4, j = tid & 15;
    bnd[tid] = xwh[cutf(k) * NG + j];
  }
  __syncthreads();

  // ---- Phase C: Chen tree-combine via 2 LDS slots (overlay dead xw region).
  float* slot0 = xwh;
  float* slot1 = xwh + 4352;
  float* sigb  = xwh + 8704;
  auto writeSlot = [&](float* slot) {
#pragma unroll
    for (int m = 0; m < 4; ++m) slot[64 * m + ln] = s2[m];  // index == a*16+b
    float* s3s = slot + 256;
#pragma unroll
    for (int m = 0; m < 4; ++m)
#pragma unroll
      for (int cc = 0; cc < 16; ++cc)
        s3s[64 * ln + ((m * 16 + cc) ^ (ln & 31))] = s3[m][cc];
  };
  // A (regs) <- A ⊗ B (slot). Segments in bnd-row indices: A=[as,ae], B=[bs,be] (ae==bs).
  auto combineSlot = [&](const float* slot, int as_, int ae_, int bs_, int be_) {
    const float* s2b = slot;
    const float* s3b = slot + 256;
    float s1b[16];
#pragma unroll
    for (int cc = 0; cc < 16; ++cc) s1b[cc] = bnd[be_ * 16 + cc] - bnd[bs_ * 16 + cc];
    float s1bb = bnd[be_ * 16 + bi] - bnd[bs_ * 16 + bi];
    float s1aa[4];
#pragma unroll
    for (int m = 0; m < 4; ++m) {
      int a = 4 * m + hi;
      s1aa[m] = bnd[ae_ * 16 + a] - bnd[as_ * 16 + a];
    }
    float row[16];
#pragma unroll
    for (int cc = 0; cc < 16; ++cc) row[cc] = s2b[bi * 16 + cc];
#pragma unroll
    for (int m = 0; m < 4; ++m) {
      float s2bo = s2b[64 * m + ln];
#pragma unroll
      for (int cc = 0; cc < 16; ++cc)
        s3[m][cc] += s3b[64 * ln + ((m * 16 + cc) ^ (ln & 31))]
                   + s2[m] * s1b[cc] + s1aa[m] * row[cc];   // uses OLD s2 (S2a)
      s2[m] += s2bo + s1aa[m] * s1bb;
    }
  };
  // Round 1a: chunks (0,1) and (2,3)
  if (ch == 1) writeSlot(slot0);
  if (ch == 3) writeSlot(slot1);
  __syncthreads();
  if (ch == 0) combineSlot(slot0, 0, 1, 1, 2);
  if (ch == 2) combineSlot(slot1, 2, 3, 3, 4);
  __syncthreads();
  // Round 1b: chunks (4,5) and (6,7)
  if (ch == 5) writeSlot(slot0);
  if (ch == 7) writeSlot(slot1);
  __syncthreads();
  if (ch == 4) combineSlot(slot0, 4, 5, 5, 6);
  if (ch == 6) combineSlot(slot1, 6, 7, 7, 8);
  __syncthreads();
  // Round 2: (01,23) and (45,67)
  if (ch == 2) writeSlot(slot0);
  if (ch == 6) writeSlot(slot1);
  __syncthreads();
  if (ch == 0) combineSlot(slot0, 0, 2, 2, 4);
  if (ch == 4) combineSlot(slot1, 4, 6, 6, 8);
  __syncthreads();
  // Round 3: (0123, 4567)
  if (ch == 4) writeSlot(slot0);
  __syncthreads();
  if (ch == 0) {
    combineSlot(slot0, 0, 4, 4, 8);
    // write sig = [S1(16) | S2(256) | S3(4096)] into LDS sig buffer
    if (ln < 16) sigb[ln] = bnd[8 * 16 + ln] - bnd[ln];   // S1 = h[511]-h[0]
#pragma unroll
    for (int m = 0; m < 4; ++m) sigb[16 + 64 * m + ln] = s2[m];
#pragma unroll
    for (int m = 0; m < 4; ++m) {
#pragma unroll
      for (int qq = 0; qq < 4; ++qq) {
        float4 v;
        v.x = s3[m][4*qq+0]; v.y = s3[m][4*qq+1]; v.z = s3[m][4*qq+2]; v.w = s3[m][4*qq+3];
        *(float4*)(sigb + 272 + 1024 * m + 256 * hi + 16 * bi + 4 * qq) = v;
      }
    }
  }
  __syncthreads();

  // ---- Phase D: FC. out[b][o] = sig·fc_w[o] + fc_b[o], all 512 threads.
  {
    float acc[10];
#pragma unroll
    for (int o = 0; o < 10; ++o) acc[o] = 0.f;
    for (int k = tid; k < SIGD; k += 512) {
      float s = sigb[k];
#pragma unroll
      for (int o = 0; o < 10; ++o) acc[o] += s * fcw[o * SIGD + k];
    }
#pragma unroll
    for (int o = 0; o < 10; ++o) {
      float v = acc[o];
#pragma unroll
      for (int off = 32; off > 0; off >>= 1) v += __shfl_down(v, off);
      if (ln == 0) bnd[wv * 10 + o] = v;    // bnd region is dead after phase C
    }
    __syncthreads();
    if (tid < 10) {
      float s = fcb[tid];
#pragma unroll
      for (int w = 0; w < 8; ++w) s += bnd[w * 10 + tid];
      out[b * 10 + tid] = s;
    }
  }
}

extern "C" void kernel_launch(void* const* d_in, const int* in_sizes, int n_in,
                              void* d_out, int out_size, void* d_ws, size_t ws_size,
                              hipStream_t stream) {
  const float* X   = (const float*)d_in[0];
  const float* Wih = (const float*)d_in[1];
  const float* Whh = (const float*)d_in[2];
  const float* bih = (const float*)d_in[3];
  const float* bhh = (const float*)d_in[4];
  const float* fcw = (const float*)d_in[5];
  const float* fcb = (const float*)d_in[6];
  float* out = (float*)d_out;
  k_main<<<NB, 512, 0, stream>>>(X, Wih, bih, bhh, Whh, fcw, fcb, out);
}

// Round 9
// 196.793 us; speedup vs baseline: 1.4487x; 1.0569x over previous
//
#include <hip/hip_runtime.h>

#define NB 256
#define NL 512
#define NI 32
#define NH 16
#define NG 64
#define SIGD 4368
#define XS 516   // xwT row stride (floats): odd-ish pad, 16B-aligned rows

__device__ __forceinline__ float RL(float v, int lane) {
  return __builtin_bit_cast(float, __builtin_amdgcn_readlane(__builtin_bit_cast(int, v), lane));
}
template<int CTRL>
__device__ __forceinline__ float QB(float v) {
  // quad_perm broadcast within each 4-lane quad (VALU DPP, no LDS)
  return __builtin_bit_cast(float, __builtin_amdgcn_update_dpp(
      0, __builtin_bit_cast(int, v), CTRL, 0xF, 0xF, true));
}
__device__ __forceinline__ int cutf(int k) {
  // R2 cuts: two small tail chunks (0: wave0 post-LSTM, 7: wave7 after prog=511)
  switch (k) {
    case 1: return 24;  case 2: return 102; case 3: return 180; case 4: return 258;
    case 5: return 335; case 6: return 412; case 7: return 488; case 8: return 511;
    default: return 0;
  }
}

// Single kernel. Phase 0: xw -> LDS TRANSPOSED (xwT[g*XS + t]). Phase A: wave0
// LSTM; xval via 1 ds_read_b128 per 4 steps, 13-16-step lookahead (lgkm slack),
// readlane matvec, h store into dead xwT columns. Phase B: chunked signatures.
// Phase C: Chen tree-combine (slots overlay xwT). Phase D: FC epilogue.
__global__ __launch_bounds__(512, 1) void k_main(const float* __restrict__ X,
    const float* __restrict__ Wih, const float* __restrict__ bih,
    const float* __restrict__ bhh, const float* __restrict__ Whh,
    const float* __restrict__ fcw, const float* __restrict__ fcb,
    float* __restrict__ out) {
  // xwT[g*XS + t]: gate g's preactivation for step t. h[t][j] overlays
  // xwT[j*XS + t] once column t is consumed (13+-step lookahead guarantees
  // consumption first). Phase C overlays slot0=xwT[0,4352), slot1=[4352,8704),
  // sigb=[8704,13072) after phase B completes.
  __shared__ __align__(16) float xwT[NG * XS];    // 132,096 B
  __shared__ __align__(16) float bnd[144];        // 9 boundary rows; later FC partials
  __shared__ int prog;                            // highest h row published by wave0
  int tid = threadIdx.x;
  int wv = tid >> 6;
  int ln = tid & 63;
  int b = blockIdx.x;

  if (tid == 0) prog = -1;

  // ---- Phase 0: xw[g][t] = X[b,t,:]·W_ih[g,:] + b_ih[g] + b_hh[g] -> xwT.
  // Wave wv does rows [64wv, 64wv+64). Lane = gate. X loads wave-uniform.
  {
    float w2[NI];
#pragma unroll
    for (int i = 0; i < 8; ++i) {
      float4 v = *(const float4*)(Wih + ln * NI + 4 * i);
      w2[4*i+0] = v.x; w2[4*i+1] = v.y; w2[4*i+2] = v.z; w2[4*i+3] = v.w;
    }
    float bias = bih[ln] + bhh[ln];
    const float* xb = X + (size_t)b * NL * NI;
#pragma unroll 4
    for (int t = 64 * wv; t < 64 * (wv + 1); ++t) {
      const float4* xr = (const float4*)(xb + t * NI);
      float x0 = bias, x1 = 0.f, x2 = 0.f, x3 = 0.f;
#pragma unroll
      for (int i = 0; i < 8; ++i) {
        float4 xv = xr[i];
        x0 += xv.x * w2[4*i+0]; x1 += xv.y * w2[4*i+1];
        x2 += xv.z * w2[4*i+2]; x3 += xv.w * w2[4*i+3];
      }
      xwT[ln * XS + t] = (x0 + x1) + (x2 + x3);   // transposed store
    }
  }
  __syncthreads();

  // ---- Phase A (wave 0): LSTM, quad layout. lane = 4*unit + gate_type (i,f,g,o).
  if (wv == 0) {
    const int q = ln & 3;
    const int j = ln >> 2;
    const int gmem = q * 16 + j;               // gate index in memory order
    float w[NH];                               // W_hh row
#pragma unroll
    for (int qq = 0; qq < 4; ++qq) {
      float4 v = *(const float4*)(Whh + gmem * NH + 4 * qq);
      w[4*qq+0] = v.x; w[4*qq+1] = v.y; w[4*qq+2] = v.z; w[4*qq+3] = v.w;
    }
    const bool isg = (q == 2);
    const float K  = isg ? 2.885390082f : -1.442695041f; // exp2 scale: tanh vs sigmoid
    const float Av = isg ? -2.0f : 1.0f;
    const float Bv = isg ? 1.0f : 0.0f;
    const float* xt = xwT + gmem * XS;         // this gate's xval stream
    float4 xq[4];                              // 16 steps of xval in flight
#pragma unroll
    for (int i = 0; i < 4; ++i) xq[i] = *(const float4*)(xt + 4 * i);
    float c = 0.0f, hval = 0.0f;
    for (int tb = 0; tb < NL; tb += 16) {
#pragma unroll
      for (int k = 0; k < 16; ++k) {
        int t = tb + k;
        // h·W_hh via v_readlane (h_u on lanes 4u..4u+3); no memory on chain
        float a0 = 0.f, a1 = 0.f, a2 = 0.f, a3 = 0.f;
#pragma unroll
        for (int jj = 0; jj < 4; ++jj) {
          a0 += RL(hval, 16*jj + 0)  * w[4*jj + 0];
          a1 += RL(hval, 16*jj + 4)  * w[4*jj + 1];
          a2 += RL(hval, 16*jj + 8)  * w[4*jj + 2];
          a3 += RL(hval, 16*jj + 12) * w[4*jj + 3];
        }
        // consume BEFORE the refill below can overwrite this buffer (R8 bug fix)
        float xval = ((const float*)xq)[k];
        // refill one buffer per 4 steps, 13-16 steps ahead of consumption
        if ((k & 3) == 3 && t + 16 < NL)
          xq[k >> 2] = *(const float4*)(xt + (t + 13));
        float acc = ((a0 + a1) + (a2 + a3)) + xval;
        float e = __builtin_amdgcn_exp2f(K * acc);
        float r = __builtin_amdgcn_rcpf(1.0f + e);
        float val = __builtin_fmaf(Av, r, Bv);
        float iv = QB<0x00>(val);
        float fv = QB<0x55>(val);
        float gv = QB<0xAA>(val);
        float ov = QB<0xFF>(val);
        c = __builtin_fmaf(fv, c, iv * gv);
        float e2 = __builtin_amdgcn_exp2f(2.885390082f * c);
        float tc = __builtin_fmaf(-2.0f, __builtin_amdgcn_rcpf(1.0f + e2), 1.0f);
        hval = ov * tc;
        xwT[j * XS + t] = hval;                // h[t][j]: all 4 quad lanes, same value
      }
      // plain flag publish: same-wave LDS ops complete in order; no waitcnt drain
      __asm__ __volatile__("" ::: "memory");
      if (ln == 0) *(volatile int*)&prog = tb + 15;
    }
  }

  // ---- Phase B: chunked signatures (h row t: h[t][j] = xwT[j*XS + t]).
  // Lane ln owns S3[a][b][c] for a=4m+(ln>>4), b=ln&15, c=0..15; S2[a][b] same (a,b).
  const int bi = ln & 15;
  const int hi = ln >> 4;
  const int ch = wv;                           // chunk == wave (R2 mapping)
  int ts = cutf(ch);
  int te = cutf(ch + 1);
  while (*(volatile int*)&prog < te) __builtin_amdgcn_s_sleep(2);
  __asm__ __volatile__("" ::: "memory");

  float s3[4][16];
  float s2[4] = {0.f, 0.f, 0.f, 0.f};
#pragma unroll
  for (int m = 0; m < 4; ++m)
#pragma unroll
    for (int cc = 0; cc < 16; ++cc) s3[m][cc] = 0.f;
  float hc[16];
#pragma unroll
  for (int cc = 0; cc < 16; ++cc) hc[cc] = xwT[cc * XS + ts];   // uniform reads
  float hcb = xwT[bi * XS + ts];
  float hca[4], h0a[4];
#pragma unroll
  for (int m = 0; m < 4; ++m) { hca[m] = xwT[(4 * m + hi) * XS + ts]; h0a[m] = hca[m]; }
  for (int t = ts; t < te; ++t) {
    int tn = t + 1;
    float hn[16];
#pragma unroll
    for (int cc = 0; cc < 16; ++cc) hn[cc] = xwT[cc * XS + tn];
    float hnb = xwT[bi * XS + tn];
    float d[16];
#pragma unroll
    for (int cc = 0; cc < 16; ++cc) d[cc] = hn[cc] - hc[cc];
    float db = hnb - hcb;
    float P[4];
#pragma unroll
    for (int m = 0; m < 4; ++m) {
      float hna = xwT[(4 * m + hi) * XS + tn];
      float da = hna - hca[m];
      float s1 = hca[m] - h0a[m];                      // S1[a] pre-increment (telescoping)
      P[m] = s2[m] + db * (0.5f * s1 + 0.166666666667f * da);
      s2[m] += db * (s1 + 0.5f * da);                  // S2 += e2 + S1(x)e1
      hca[m] = hna;
    }
#pragma unroll
    for (int m = 0; m < 4; ++m)
#pragma unroll
      for (int cc = 0; cc < 16; ++cc)
        s3[m][cc] += P[m] * d[cc];                     // S3 += e3 + S2(x)e1 + S1(x)e2
#pragma unroll
    for (int cc = 0; cc < 16; ++cc) hc[cc] = hn[cc];
    hcb = hnb;
  }
  __syncthreads();

  // save boundary rows h[cut(k)][j] (k=0..8) before slots overwrite the region
  if (tid < 144) {
    int k = tid >> 4, j = tid & 15;
    bnd[tid] = xwT[j * XS + cutf(k)];
  }
  __syncthreads();

  // ---- Phase C: Chen tree-combine via 2 LDS slots (overlay dead xwT region).
  float* slot0 = xwT;
  float* slot1 = xwT + 4352;
  float* sigb  = xwT + 8704;
  auto writeSlot = [&](float* slot) {
#pragma unroll
    for (int m = 0; m < 4; ++m) slot[64 * m + ln] = s2[m];  // index == a*16+b
    float* s3s = slot + 256;
#pragma unroll
    for (int m = 0; m < 4; ++m)
#pragma unroll
      for (int cc = 0; cc < 16; ++cc)
        s3s[64 * ln + ((m * 16 + cc) ^ (ln & 31))] = s3[m][cc];
  };
  // A (regs) <- A ⊗ B (slot). Segments in bnd-row indices: A=[as,ae], B=[bs,be] (ae==bs).
  auto combineSlot = [&](const float* slot, int as_, int ae_, int bs_, int be_) {
    const float* s2b = slot;
    const float* s3b = slot + 256;
    float s1b[16];
#pragma unroll
    for (int cc = 0; cc < 16; ++cc) s1b[cc] = bnd[be_ * 16 + cc] - bnd[bs_ * 16 + cc];
    float s1bb = bnd[be_ * 16 + bi] - bnd[bs_ * 16 + bi];
    float s1aa[4];
#pragma unroll
    for (int m = 0; m < 4; ++m) {
      int a = 4 * m + hi;
      s1aa[m] = bnd[ae_ * 16 + a] - bnd[as_ * 16 + a];
    }
    float row[16];
#pragma unroll
    for (int cc = 0; cc < 16; ++cc) row[cc] = s2b[bi * 16 + cc];
#pragma unroll
    for (int m = 0; m < 4; ++m) {
      float s2bo = s2b[64 * m + ln];
#pragma unroll
      for (int cc = 0; cc < 16; ++cc)
        s3[m][cc] += s3b[64 * ln + ((m * 16 + cc) ^ (ln & 31))]
                   + s2[m] * s1b[cc] + s1aa[m] * row[cc];   // uses OLD s2 (S2a)
      s2[m] += s2bo + s1aa[m] * s1bb;
    }
  };
  // Round 1a: chunks (0,1) and (2,3)
  if (ch == 1) writeSlot(slot0);
  if (ch == 3) writeSlot(slot1);
  __syncthreads();
  if (ch == 0) combineSlot(slot0, 0, 1, 1, 2);
  if (ch == 2) combineSlot(slot1, 2, 3, 3, 4);
  __syncthreads();
  // Round 1b: chunks (4,5) and (6,7)
  if (ch == 5) writeSlot(slot0);
  if (ch == 7) writeSlot(slot1);
  __syncthreads();
  if (ch == 4) combineSlot(slot0, 4, 5, 5, 6);
  if (ch == 6) combineSlot(slot1, 6, 7, 7, 8);
  __syncthreads();
  // Round 2: (01,23) and (45,67)
  if (ch == 2) writeSlot(slot0);
  if (ch == 6) writeSlot(slot1);
  __syncthreads();
  if (ch == 0) combineSlot(slot0, 0, 2, 2, 4);
  if (ch == 4) combineSlot(slot1, 4, 6, 6, 8);
  __syncthreads();
  // Round 3: (0123, 4567)
  if (ch == 4) writeSlot(slot0);
  __syncthreads();
  if (ch == 0) {
    combineSlot(slot0, 0, 4, 4, 8);
    // write sig = [S1(16) | S2(256) | S3(4096)] into LDS sig buffer
    if (ln < 16) sigb[ln] = bnd[8 * 16 + ln] - bnd[ln];   // S1 = h[511]-h[0]
#pragma unroll
    for (int m = 0; m < 4; ++m) sigb[16 + 64 * m + ln] = s2[m];
#pragma unroll
    for (int m = 0; m < 4; ++m) {
#pragma unroll
      for (int qq = 0; qq < 4; ++qq) {
        float4 v;
        v.x = s3[m][4*qq+0]; v.y = s3[m][4*qq+1]; v.z = s3[m][4*qq+2]; v.w = s3[m][4*qq+3];
        *(float4*)(sigb + 272 + 1024 * m + 256 * hi + 16 * bi + 4 * qq) = v;
      }
    }
  }
  __syncthreads();

  // ---- Phase D: FC. out[b][o] = sig·fc_w[o] + fc_b[o], all 512 threads.
  {
    float acc[10];
#pragma unroll
    for (int o = 0; o < 10; ++o) acc[o] = 0.f;
    for (int k = tid; k < SIGD; k += 512) {
      float s = sigb[k];
#pragma unroll
      for (int o = 0; o < 10; ++o) acc[o] += s * fcw[o * SIGD + k];
    }
#pragma unroll
    for (int o = 0; o < 10; ++o) {
      float v = acc[o];
#pragma unroll
      for (int off = 32; off > 0; off >>= 1) v += __shfl_down(v, off);
      if (ln == 0) bnd[wv * 10 + o] = v;    // bnd region is dead after phase C
    }
    __syncthreads();
    if (tid < 10) {
      float s = fcb[tid];
#pragma unroll
      for (int w = 0; w < 8; ++w) s += bnd[w * 10 + tid];
      out[b * 10 + tid] = s;
    }
  }
}

extern "C" void kernel_launch(void* const* d_in, const int* in_sizes, int n_in,
                              void* d_out, int out_size, void* d_ws, size_t ws_size,
                              hipStream_t stream) {
  const float* X   = (const float*)d_in[0];
  const float* Wih = (const float*)d_in[1];
  const float* Whh = (const float*)d_in[2];
  const float* bih = (const float*)d_in[3];
  const float* bhh = (const float*)d_in[4];
  const float* fcw = (const float*)d_in[5];
  const float* fcb = (const float*)d_in[6];
  float* out = (float*)d_out;
  k_main<<<NB, 512, 0, stream>>>(X, Wih, bih, bhh, Whh, fcw, fcb, out);
}

// Round 10
// 195.391 us; speedup vs baseline: 1.4591x; 1.0072x over previous
//
#include <hip/hip_runtime.h>

#define NB 256
#define NL 512
#define NI 32
#define NH 16
#define NG 64
#define SIGD 4368
#define XS 516   // xwT row stride (floats): pad -> strided access lands 2-way (free)

__device__ __forceinline__ float RL(float v, int lane) {
  return __builtin_bit_cast(float, __builtin_amdgcn_readlane(__builtin_bit_cast(int, v), lane));
}
template<int CTRL>
__device__ __forceinline__ float QB(float v) {
  // quad_perm broadcast within each 4-lane quad (VALU DPP, no LDS)
  return __builtin_bit_cast(float, __builtin_amdgcn_update_dpp(
      0, __builtin_bit_cast(int, v), CTRL, 0xF, 0xF, true));
}
__device__ __forceinline__ int cutf(int k) {
  switch (k) {
    case 1: return 24;  case 2: return 102; case 3: return 180; case 4: return 258;
    case 5: return 335; case 6: return 412; case 7: return 488; case 8: return 511;
    default: return 0;
  }
}

// Single kernel. Phase 0: xw -> LDS transposed, PRE-SCALED by K_g (exp2 gate
// constant folded into data). Phase A: wave0 LSTM; K-scaled weights, batched
// readlanes, scaled-c recurrence, guarded h-store, setprio 3. Phase B: chunked
// signatures. Phase C: Chen tree-combine. Phase D: FC epilogue.
__global__ __launch_bounds__(512, 1) void k_main(const float* __restrict__ X,
    const float* __restrict__ Wih, const float* __restrict__ bih,
    const float* __restrict__ bhh, const float* __restrict__ Whh,
    const float* __restrict__ fcw, const float* __restrict__ fcb,
    float* __restrict__ out) {
  __shared__ __align__(16) float xwT[NG * XS];    // 132,096 B
  __shared__ __align__(16) float bnd[144];
  __shared__ int prog;
  int tid = threadIdx.x;
  int wv = tid >> 6;
  int ln = tid & 63;
  int b = blockIdx.x;

  if (tid == 0) prog = -1;

  // ---- Phase 0: xwT[g][t] = K_g * (X[b,t,:]·W_ih[g,:] + b_ih[g] + b_hh[g]).
  {
    const float Kg = (ln >= 32 && ln < 48) ? 2.885390082f : -1.442695041f;
    float w2[NI];
#pragma unroll
    for (int i = 0; i < 8; ++i) {
      float4 v = *(const float4*)(Wih + ln * NI + 4 * i);
      w2[4*i+0] = v.x; w2[4*i+1] = v.y; w2[4*i+2] = v.z; w2[4*i+3] = v.w;
    }
    float bias = bih[ln] + bhh[ln];
    const float* xb = X + (size_t)b * NL * NI;
#pragma unroll 4
    for (int t = 64 * wv; t < 64 * (wv + 1); ++t) {
      const float4* xr = (const float4*)(xb + t * NI);
      float x0 = bias, x1 = 0.f, x2 = 0.f, x3 = 0.f;
#pragma unroll
      for (int i = 0; i < 8; ++i) {
        float4 xv = xr[i];
        x0 += xv.x * w2[4*i+0]; x1 += xv.y * w2[4*i+1];
        x2 += xv.z * w2[4*i+2]; x3 += xv.w * w2[4*i+3];
      }
      xwT[ln * XS + t] = Kg * ((x0 + x1) + (x2 + x3));   // K pre-folded
    }
  }
  __syncthreads();

  // ---- Phase A (wave 0): LSTM, quad layout. lane = 4*unit + gate_type (i,f,g,o).
  if (wv == 0) {
    __asm__ __volatile__("s_setprio 3");
    const int q = ln & 3;
    const int j = ln >> 2;
    const int gmem = q * 16 + j;
    const bool isg = (q == 2);
    const float Kg = isg ? 2.885390082f : -1.442695041f;
    const float Av = isg ? -2.0f : 1.0f;
    const float Bv = isg ? 1.0f : 0.0f;
    const float CT = 2.885390082f;
    float w[NH];                               // K-scaled W_hh row
#pragma unroll
    for (int qq = 0; qq < 4; ++qq) {
      float4 v = *(const float4*)(Whh + gmem * NH + 4 * qq);
      w[4*qq+0] = Kg*v.x; w[4*qq+1] = Kg*v.y; w[4*qq+2] = Kg*v.z; w[4*qq+3] = Kg*v.w;
    }
    const float* xt = xwT + gmem * XS;
    float4 xq[4];                              // 16 steps of K-scaled xval in flight
#pragma unroll
    for (int i = 0; i < 4; ++i) xq[i] = *(const float4*)(xt + 4 * i);
    float cs = 0.0f, hval = 0.0f;              // cs = CT * c  (scaled cell state)
    for (int tb = 0; tb < NL; tb += 16) {
#pragma unroll
      for (int k = 0; k < 16; ++k) {
        int t = tb + k;
        // batched readlanes: all 16 h broadcasts BEFORE any FMA (hazard x1)
        float hs[16];
#pragma unroll
        for (int u = 0; u < 16; ++u) hs[u] = RL(hval, 4 * u);
        float xval = ((const float*)xq)[k];    // consume before refill (R8 fix)
        if ((k & 3) == 3 && t + 16 < NL)
          xq[k >> 2] = *(const float4*)(xt + (t + 13));
        float a0 = xval, a1 = 0.f, a2 = 0.f, a3 = 0.f;
#pragma unroll
        for (int u = 0; u < 4; ++u) {
          a0 += hs[4*u+0] * w[4*u+0];
          a1 += hs[4*u+1] * w[4*u+1];
          a2 += hs[4*u+2] * w[4*u+2];
          a3 += hs[4*u+3] * w[4*u+3];
        }
        float acc = (a0 + a1) + (a2 + a3);     // already K-scaled
        float e = __builtin_amdgcn_exp2f(acc);
        float r = __builtin_amdgcn_rcpf(1.0f + e);
        float val = __builtin_fmaf(Av, r, Bv);
        float iv = QB<0x00>(val);
        float fv = QB<0x55>(val);
        float gv = QB<0xAA>(val);
        float ov = QB<0xFF>(val);
        cs = __builtin_fmaf(fv, cs, (CT * iv) * gv);   // scaled-c recurrence
        float e2 = __builtin_amdgcn_exp2f(cs);
        float tc = __builtin_fmaf(-2.0f, __builtin_amdgcn_rcpf(1.0f + e2), 1.0f);
        hval = ov * tc;
        if (q == 0) xwT[j * XS + t] = hval;    // guarded: 16 lanes, distinct banks
      }
      __asm__ __volatile__("" ::: "memory");
      if (ln == 0) *(volatile int*)&prog = tb + 15;
    }
    __asm__ __volatile__("s_setprio 0");
  }

  // ---- Phase B: chunked signatures (h row t: h[t][j] = xwT[j*XS + t]).
  const int bi = ln & 15;
  const int hi = ln >> 4;
  const int ch = wv;
  int ts = cutf(ch);
  int te = cutf(ch + 1);
  while (*(volatile int*)&prog < te) __builtin_amdgcn_s_sleep(8);
  __asm__ __volatile__("" ::: "memory");

  float s3[4][16];
  float s2[4] = {0.f, 0.f, 0.f, 0.f};
#pragma unroll
  for (int m = 0; m < 4; ++m)
#pragma unroll
    for (int cc = 0; cc < 16; ++cc) s3[m][cc] = 0.f;
  float hc[16];
#pragma unroll
  for (int cc = 0; cc < 16; ++cc) hc[cc] = xwT[cc * XS + ts];   // uniform reads
  float hcb = xwT[bi * XS + ts];
  float hca[4], h0a[4];
#pragma unroll
  for (int m = 0; m < 4; ++m) { hca[m] = xwT[(4 * m + hi) * XS + ts]; h0a[m] = hca[m]; }
  for (int t = ts; t < te; ++t) {
    int tn = t + 1;
    float hn[16];
#pragma unroll
    for (int cc = 0; cc < 16; ++cc) hn[cc] = xwT[cc * XS + tn];
    float hnb = xwT[bi * XS + tn];
    float d[16];
#pragma unroll
    for (int cc = 0; cc < 16; ++cc) d[cc] = hn[cc] - hc[cc];
    float db = hnb - hcb;
    float P[4];
#pragma unroll
    for (int m = 0; m < 4; ++m) {
      float hna = xwT[(4 * m + hi) * XS + tn];
      float da = hna - hca[m];
      float s1 = hca[m] - h0a[m];                      // S1[a] pre-increment (telescoping)
      P[m] = s2[m] + db * (0.5f * s1 + 0.166666666667f * da);
      s2[m] += db * (s1 + 0.5f * da);                  // S2 += e2 + S1(x)e1
      hca[m] = hna;
    }
#pragma unroll
    for (int m = 0; m < 4; ++m)
#pragma unroll
      for (int cc = 0; cc < 16; ++cc)
        s3[m][cc] += P[m] * d[cc];                     // S3 += e3 + S2(x)e1 + S1(x)e2
#pragma unroll
    for (int cc = 0; cc < 16; ++cc) hc[cc] = hn[cc];
    hcb = hnb;
  }
  __syncthreads();

  // save boundary rows h[cut(k)][j] (k=0..8) before slots overwrite the region
  if (tid < 144) {
    int k = tid >> 4, j = tid & 15;
    bnd[tid] = xwT[j * XS + cutf(k)];
  }
  __syncthreads();

  // ---- Phase C: Chen tree-combine via 2 LDS slots (overlay dead xwT region).
  float* slot0 = xwT;
  float* slot1 = xwT + 4352;
  float* sigb  = xwT + 8704;
  auto writeSlot = [&](float* slot) {
#pragma unroll
    for (int m = 0; m < 4; ++m) slot[64 * m + ln] = s2[m];  // index == a*16+b
    float* s3s = slot + 256;
#pragma unroll
    for (int m = 0; m < 4; ++m)
#pragma unroll
      for (int cc = 0; cc < 16; ++cc)
        s3s[64 * ln + ((m * 16 + cc) ^ (ln & 31))] = s3[m][cc];
  };
  auto combineSlot = [&](const float* slot, int as_, int ae_, int bs_, int be_) {
    const float* s2b = slot;
    const float* s3b = slot + 256;
    float s1b[16];
#pragma unroll
    for (int cc = 0; cc < 16; ++cc) s1b[cc] = bnd[be_ * 16 + cc] - bnd[bs_ * 16 + cc];
    float s1bb = bnd[be_ * 16 + bi] - bnd[bs_ * 16 + bi];
    float s1aa[4];
#pragma unroll
    for (int m = 0; m < 4; ++m) {
      int a = 4 * m + hi;
      s1aa[m] = bnd[ae_ * 16 + a] - bnd[as_ * 16 + a];
    }
    float row[16];
#pragma unroll
    for (int cc = 0; cc < 16; ++cc) row[cc] = s2b[bi * 16 + cc];
#pragma unroll
    for (int m = 0; m < 4; ++m) {
      float s2bo = s2b[64 * m + ln];
#pragma unroll
      for (int cc = 0; cc < 16; ++cc)
        s3[m][cc] += s3b[64 * ln + ((m * 16 + cc) ^ (ln & 31))]
                   + s2[m] * s1b[cc] + s1aa[m] * row[cc];   // uses OLD s2 (S2a)
      s2[m] += s2bo + s1aa[m] * s1bb;
    }
  };
  // Round 1a: chunks (0,1) and (2,3)
  if (ch == 1) writeSlot(slot0);
  if (ch == 3) writeSlot(slot1);
  __syncthreads();
  if (ch == 0) combineSlot(slot0, 0, 1, 1, 2);
  if (ch == 2) combineSlot(slot1, 2, 3, 3, 4);
  __syncthreads();
  // Round 1b: chunks (4,5) and (6,7)
  if (ch == 5) writeSlot(slot0);
  if (ch == 7) writeSlot(slot1);
  __syncthreads();
  if (ch == 4) combineSlot(slot0, 4, 5, 5, 6);
  if (ch == 6) combineSlot(slot1, 6, 7, 7, 8);
  __syncthreads();
  // Round 2: (01,23) and (45,67)
  if (ch == 2) writeSlot(slot0);
  if (ch == 6) writeSlot(slot1);
  __syncthreads();
  if (ch == 0) combineSlot(slot0, 0, 2, 2, 4);
  if (ch == 4) combineSlot(slot1, 4, 6, 6, 8);
  __syncthreads();
  // Round 3: (0123, 4567)
  if (ch == 4) writeSlot(slot0);
  __syncthreads();
  if (ch == 0) {
    combineSlot(slot0, 0, 4, 4, 8);
    if (ln < 16) sigb[ln] = bnd[8 * 16 + ln] - bnd[ln];   // S1 = h[511]-h[0]
#pragma unroll
    for (int m = 0; m < 4; ++m) sigb[16 + 64 * m + ln] = s2[m];
#pragma unroll
    for (int m = 0; m < 4; ++m) {
#pragma unroll
      for (int qq = 0; qq < 4; ++qq) {
        float4 v;
        v.x = s3[m][4*qq+0]; v.y = s3[m][4*qq+1]; v.z = s3[m][4*qq+2]; v.w = s3[m][4*qq+3];
        *(float4*)(sigb + 272 + 1024 * m + 256 * hi + 16 * bi + 4 * qq) = v;
      }
    }
  }
  __syncthreads();

  // ---- Phase D: FC. out[b][o] = sig·fc_w[o] + fc_b[o], all 512 threads.
  {
    float acc[10];
#pragma unroll
    for (int o = 0; o < 10; ++o) acc[o] = 0.f;
    for (int k = tid; k < SIGD; k += 512) {
      float s = sigb[k];
#pragma unroll
      for (int o = 0; o < 10; ++o) acc[o] += s * fcw[o * SIGD + k];
    }
#pragma unroll
    for (int o = 0; o < 10; ++o) {
      float v = acc[o];
#pragma unroll
      for (int off = 32; off > 0; off >>= 1) v += __shfl_down(v, off);
      if (ln == 0) bnd[wv * 10 + o] = v;
    }
    __syncthreads();
    if (tid < 10) {
      float s = fcb[tid];
#pragma unroll
      for (int w = 0; w < 8; ++w) s += bnd[w * 10 + tid];
      out[b * 10 + tid] = s;
    }
  }
}

extern "C" void kernel_launch(void* const* d_in, const int* in_sizes, int n_in,
                              void* d_out, int out_size, void* d_ws, size_t ws_size,
                              hipStream_t stream) {
  const float* X   = (const float*)d_in[0];
  const float* Wih = (const float*)d_in[1];
  const float* Whh = (const float*)d_in[2];
  const float* bih = (const float*)d_in[3];
  const float* bhh = (const float*)d_in[4];
  const float* fcw = (const float*)d_in[5];
  const float* fcb = (const float*)d_in[6];
  float* out = (float*)d_out;
  k_main<<<NB, 512, 0, stream>>>(X, Wih, bih, bhh, Whh, fcw, fcb, out);
}